// Round 5
// baseline (710.488 us; speedup 1.0000x reference)
//
#include <hip/hip_runtime.h>
#include <hip/hip_bf16.h>

#define M_ROWS 8192      // B*L
#define DM 256           // D_MODEL
#define DI 512           // D_INNER
#define DS 16            // D_STATE
#define DTR 16           // DT_RANK
#define LSEQ 1024
#define NC 64            // chunks per sequence
#define CT 16            // chunk length (NC*CT == LSEQ)

typedef __bf16 bf16x8 __attribute__((ext_vector_type(8)));
typedef float  f32x4  __attribute__((ext_vector_type(4)));

__device__ __forceinline__ bf16x8 ld8(const __hip_bfloat16* p) {
    uint4 u = *(const uint4*)p;
    return __builtin_bit_cast(bf16x8, u);
}

// ---------------------------------------------------------------------------
// bf16 MFMA GEMM, per-wave 16(M)x64(N) tile, 4 waves stacked in M (block 64xM).
// A: MxK bf16 rm.  W: NxK bf16 rm.
// MODE 0: C fp32 = acc + bias[n]
// MODE 1: C fp32 += alpha * acc
// MODE 2: split bf16: col<DI -> O1[row*DI+col], else O2[row*DI+col-DI] (N=1024)
// ---------------------------------------------------------------------------
template<int MODE>
__global__ __launch_bounds__(256)
void gemm_bt16(const __hip_bfloat16* __restrict__ A,
               const __hip_bfloat16* __restrict__ W,
               const float* __restrict__ bias,
               const float* __restrict__ alpha_p,
               float* __restrict__ C,
               __hip_bfloat16* __restrict__ O1,
               __hip_bfloat16* __restrict__ O2,
               int M, int N, int K)
{
    const int w  = threadIdx.x >> 6;
    const int l  = threadIdx.x & 63;
    const int lr = l & 15;
    const int kb = l >> 4;
    const int m0 = blockIdx.x * 64 + w * 16;
    const int n0 = blockIdx.y * 64;

    f32x4 acc[4];
    #pragma unroll
    for (int ni = 0; ni < 4; ++ni) acc[ni] = (f32x4){0.f, 0.f, 0.f, 0.f};

    const __hip_bfloat16* pA = A + (size_t)(m0 + lr) * K + kb * 8;
    const __hip_bfloat16* pW = W + (size_t)(n0 + lr) * K + kb * 8;
    const size_t sK16 = (size_t)16 * K;

    #pragma unroll 2
    for (int k0 = 0; k0 < K; k0 += 32) {
        bf16x8 a0 = ld8(pA + k0);
        bf16x8 b0 = ld8(pW + k0);
        bf16x8 b1 = ld8(pW + sK16 + k0);
        bf16x8 b2 = ld8(pW + 2 * sK16 + k0);
        bf16x8 b3 = ld8(pW + 3 * sK16 + k0);
        acc[0] = __builtin_amdgcn_mfma_f32_16x16x32_bf16(a0, b0, acc[0], 0, 0, 0);
        acc[1] = __builtin_amdgcn_mfma_f32_16x16x32_bf16(a0, b1, acc[1], 0, 0, 0);
        acc[2] = __builtin_amdgcn_mfma_f32_16x16x32_bf16(a0, b2, acc[2], 0, 0, 0);
        acc[3] = __builtin_amdgcn_mfma_f32_16x16x32_bf16(a0, b3, acc[3], 0, 0, 0);
    }

    const float alpha = (MODE == 1 && alpha_p) ? alpha_p[0] : 1.0f;
    #pragma unroll
    for (int ni = 0; ni < 4; ++ni) {
        const int col = n0 + ni * 16 + lr;
        float bv = 0.f;
        if (MODE == 0 && bias) bv = bias[col];
        #pragma unroll
        for (int r = 0; r < 4; ++r) {
            const int row = m0 + kb * 4 + r;
            const float v = acc[ni][r];
            if (MODE == 0) {
                C[(size_t)row * N + col] = v + bv;
            } else if (MODE == 1) {
                C[(size_t)row * N + col] += alpha * v;
            } else {
                if (col < DI) O1[(size_t)row * DI + col] = __float2bfloat16(v);
                else          O2[(size_t)row * DI + (col - DI)] = __float2bfloat16(v);
            }
        }
    }
}

// ---------------------------------------------------------------------------
// Fused x_proj+dt_proj GEMM (per-wave 16x64): A(8192x512) @ Wc(544x512)^T.
// cols 0..511   -> delta = softplus(acc + dtb[col])   (fp32)
// cols 512..543 -> bc[row][col-512]                   (fp32)
// ---------------------------------------------------------------------------
__global__ __launch_bounds__(256)
void gemm_dt_bc(const __hip_bfloat16* __restrict__ A,
                const __hip_bfloat16* __restrict__ Wc,
                const float* __restrict__ dtb,
                float* __restrict__ delta,
                float* __restrict__ bc)
{
    const int K = 512;
    const int w  = threadIdx.x >> 6;
    const int l  = threadIdx.x & 63;
    const int lr = l & 15;
    const int kb = l >> 4;
    const int m0 = blockIdx.x * 64 + w * 16;
    const int n0 = blockIdx.y * 64;

    f32x4 acc[4];
    #pragma unroll
    for (int ni = 0; ni < 4; ++ni) acc[ni] = (f32x4){0.f, 0.f, 0.f, 0.f};

    const int r0 = min(n0 + lr,      543);
    const int r1 = min(n0 + lr + 16, 543);
    const int r2 = min(n0 + lr + 32, 543);
    const int r3 = min(n0 + lr + 48, 543);
    const __hip_bfloat16* pA  = A  + (size_t)(m0 + lr) * K + kb * 8;
    const __hip_bfloat16* pW0 = Wc + (size_t)r0 * K + kb * 8;
    const __hip_bfloat16* pW1 = Wc + (size_t)r1 * K + kb * 8;
    const __hip_bfloat16* pW2 = Wc + (size_t)r2 * K + kb * 8;
    const __hip_bfloat16* pW3 = Wc + (size_t)r3 * K + kb * 8;

    #pragma unroll 2
    for (int k0 = 0; k0 < K; k0 += 32) {
        bf16x8 a0 = ld8(pA + k0);
        bf16x8 b0 = ld8(pW0 + k0);
        bf16x8 b1 = ld8(pW1 + k0);
        bf16x8 b2 = ld8(pW2 + k0);
        bf16x8 b3 = ld8(pW3 + k0);
        acc[0] = __builtin_amdgcn_mfma_f32_16x16x32_bf16(a0, b0, acc[0], 0, 0, 0);
        acc[1] = __builtin_amdgcn_mfma_f32_16x16x32_bf16(a0, b1, acc[1], 0, 0, 0);
        acc[2] = __builtin_amdgcn_mfma_f32_16x16x32_bf16(a0, b2, acc[2], 0, 0, 0);
        acc[3] = __builtin_amdgcn_mfma_f32_16x16x32_bf16(a0, b3, acc[3], 0, 0, 0);
    }

    #pragma unroll
    for (int ni = 0; ni < 4; ++ni) {
        const int col = n0 + ni * 16 + lr;
        #pragma unroll
        for (int r = 0; r < 4; ++r) {
            const int row = m0 + kb * 4 + r;
            float v = acc[ni][r];
            if (col < 512) {
                v += dtb[col];
                v = (v > 15.f) ? v : __logf(1.f + __expf(v));
                delta[(size_t)row * DI + col] = v;
            } else if (col < 544) {
                bc[(size_t)row * 32 + (col - 512)] = v;
            }
        }
    }
}

// ---------------------------------------------------------------------------
// Build W_comb (per layer, 544x512 bf16): rows 0..511 = dtw @ xw[0:16];
// rows 512..543 = xw[16:48].
// ---------------------------------------------------------------------------
__global__ __launch_bounds__(256)
void prep_wcomb(const float* __restrict__ xw, const float* __restrict__ dtw,
                __hip_bfloat16* __restrict__ Wc)
{
    const int idx = blockIdx.x * 256 + threadIdx.x;   // 4*544*512
    const int lyr = idx / (544 * 512);
    const int rem = idx - lyr * (544 * 512);
    const int n = rem >> 9;
    const int k = rem & 511;

    const float* xwl = xw + (size_t)lyr * 48 * 512;
    float s;
    if (n < 512) {
        const float* dtn = dtw + (size_t)lyr * 512 * 16 + n * 16;
        s = 0.f;
        #pragma unroll
        for (int r = 0; r < 16; ++r) s += dtn[r] * xwl[r * 512 + k];
    } else {
        s = xwl[(16 + n - 512) * 512 + k];
    }
    Wc[idx] = __float2bfloat16(s);
}

// ---------------------------------------------------------------------------
__global__ __launch_bounds__(256)
void cvt_bf16_kernel(const float* __restrict__ in, __hip_bfloat16* __restrict__ out,
                     int n)
{
    const int i = (blockIdx.x * 256 + threadIdx.x) * 8;
    if (i >= n) return;
    float4 a = *(const float4*)(in + i);
    float4 b = *(const float4*)(in + i + 4);
    union { __hip_bfloat16 h[8]; uint4 u; } r;
    r.h[0] = __float2bfloat16(a.x); r.h[1] = __float2bfloat16(a.y);
    r.h[2] = __float2bfloat16(a.z); r.h[3] = __float2bfloat16(a.w);
    r.h[4] = __float2bfloat16(b.x); r.h[5] = __float2bfloat16(b.y);
    r.h[6] = __float2bfloat16(b.z); r.h[7] = __float2bfloat16(b.w);
    *(uint4*)(out + i) = r.u;
}

__global__ __launch_bounds__(256)
void cvt_pad_bf16(const float* __restrict__ in, __hip_bfloat16* __restrict__ out,
                  int rows, int incols, int outcols)
{
    const int idx = blockIdx.x * 256 + threadIdx.x;
    if (idx >= rows * outcols) return;
    const int r = idx / outcols;
    const int c = idx - r * outcols;
    out[idx] = __float2bfloat16(c < incols ? in[(size_t)r * incols + c] : 0.f);
}

// ---------------------------------------------------------------------------
// LayerNorm over rows of 256: one 64-lane wave per row.
// ---------------------------------------------------------------------------
template<typename OT>
__global__ __launch_bounds__(64)
void ln_kernel(const float* __restrict__ in, const float* __restrict__ g,
               const float* __restrict__ b, OT* __restrict__ out)
{
    const int row = blockIdx.x;
    const int t = threadIdx.x;
    const float* x = in + (size_t)row * DM;

    float v[4];
    float s = 0.f;
    #pragma unroll
    for (int j = 0; j < 4; ++j) { v[j] = x[t + 64 * j]; s += v[j]; }
    #pragma unroll
    for (int m = 1; m < 64; m <<= 1) s += __shfl_xor(s, m, 64);
    const float mu = s * (1.f / DM);

    float s2 = 0.f;
    #pragma unroll
    for (int j = 0; j < 4; ++j) { float d = v[j] - mu; s2 += d * d; }
    #pragma unroll
    for (int m = 1; m < 64; m <<= 1) s2 += __shfl_xor(s2, m, 64);
    const float var = s2 * (1.f / DM);
    const float sc = 1.f / sqrtf(var + 1e-5f);

    #pragma unroll
    for (int j = 0; j < 4; ++j) {
        const int c = t + 64 * j;
        out[(size_t)row * DM + c] = (OT)((v[j] - mu) * sc * g[c] + b[c]);
    }
}

// ---------------------------------------------------------------------------
// Rolling causal conv4 + SiLU, bf16 in (xi), bf16 out (xc).
// 8 timesteps/thread; each input read once.
// ---------------------------------------------------------------------------
__global__ __launch_bounds__(256)
void conv_silu3(const __hip_bfloat16* __restrict__ xi, const float* __restrict__ cw,
                const float* __restrict__ cb, __hip_bfloat16* __restrict__ xcb)
{
    const int idx = blockIdx.x * 256 + threadIdx.x;   // 8192*512/8
    const int d = idx & (DI - 1);
    const int g = idx >> 9;
    const int b = g >> 7;
    const int l0 = (g & 127) * 8;

    const float w0 = cw[d * 4 + 0], w1 = cw[d * 4 + 1];
    const float w2 = cw[d * 4 + 2], w3 = cw[d * 4 + 3];
    const float bias = cb[d];

    const size_t base = ((size_t)b << 10);
    float xm3 = (l0 >= 3) ? __bfloat162float(xi[(base + l0 - 3) * DI + d]) : 0.f;
    float xm2 = (l0 >= 2) ? __bfloat162float(xi[(base + l0 - 2) * DI + d]) : 0.f;
    float xm1 = (l0 >= 1) ? __bfloat162float(xi[(base + l0 - 1) * DI + d]) : 0.f;

    #pragma unroll
    for (int j = 0; j < 8; ++j) {
        const size_t m = base + l0 + j;
        const float xc0 = __bfloat162float(xi[m * DI + d]);
        float acc = bias + w0 * xm3 + w1 * xm2 + w2 * xm1 + w3 * xc0;
        const float sg = 1.f / (1.f + __expf(-acc));
        xcb[m * DI + d] = __float2bfloat16(acc * sg);
        xm3 = xm2; xm2 = xm1; xm1 = xc0;
    }
}

// ---------------------------------------------------------------------------
// Chunked parallel selective scan (3 passes). u from bf16 xc, z from bf16 z_bf.
// ---------------------------------------------------------------------------
__global__ __launch_bounds__(256)
void scan_part1(const float* __restrict__ delta, const __hip_bfloat16* __restrict__ xcb,
                const float* __restrict__ bc, const float* __restrict__ A_log,
                float* __restrict__ S, float* __restrict__ Dsum)
{
    const int blk = blockIdx.x;
    const int bcx = blk >> 1;
    const int d   = ((blk & 1) << 8) + threadIdx.x;
    const int b   = bcx >> 6;
    const int c   = bcx & (NC - 1);

    float a[16], h[16];
    #pragma unroll
    for (int n = 0; n < 16; ++n) {
        a[n] = -__expf(A_log[d * 16 + n]);
        h[n] = 0.f;
    }
    float dsum = 0.f;

    const int m0 = b * LSEQ + c * CT;
    for (int t = 0; t < CT; ++t) {
        const size_t m = (size_t)(m0 + t);
        const float dt = delta[m * DI + d];
        const float u  = __bfloat162float(xcb[m * DI + d]);
        const float du = dt * u;
        dsum += dt;
        const float* Bp = bc + m * 32;
        #pragma unroll
        for (int n = 0; n < 16; ++n)
            h[n] = h[n] * __expf(dt * a[n]) + du * Bp[n];
    }
    float* Sp = S + ((size_t)bcx * DI + d) * 16;
    #pragma unroll
    for (int n = 0; n < 16; ++n) Sp[n] = h[n];
    Dsum[(size_t)bcx * DI + d] = dsum;
}

__global__ __launch_bounds__(256)
void scan_part2(const float* __restrict__ A_log, const float* __restrict__ Dsum,
                float* __restrict__ S)
{
    const int gid = blockIdx.x * 256 + threadIdx.x;
    const int n = gid & 15;
    const int d = (gid >> 4) & (DI - 1);
    const int b = gid >> 13;

    const float a = -__expf(A_log[d * 16 + n]);
    float h = 0.f;
    for (int c = 0; c < NC; ++c) {
        const size_t bcd = (size_t)(b * NC + c) * DI + d;
        const size_t idx = bcd * 16 + n;
        const float s = S[idx];
        S[idx] = h;
        h = __expf(a * Dsum[bcd]) * h + s;
    }
}

__global__ __launch_bounds__(256)
void scan_part3(const float* __restrict__ delta, const __hip_bfloat16* __restrict__ xcb,
                const float* __restrict__ bc, const __hip_bfloat16* __restrict__ z_bf,
                const float* __restrict__ A_log, const float* __restrict__ Dp,
                const float* __restrict__ H, __hip_bfloat16* __restrict__ yg)
{
    const int blk = blockIdx.x;
    const int bcx = blk >> 1;
    const int d   = ((blk & 1) << 8) + threadIdx.x;
    const int b   = bcx >> 6;
    const int c   = bcx & (NC - 1);

    float a[16], h[16];
    const float* Hp = H + ((size_t)bcx * DI + d) * 16;
    #pragma unroll
    for (int n = 0; n < 16; ++n) {
        a[n] = -__expf(A_log[d * 16 + n]);
        h[n] = Hp[n];
    }
    const float Dv = Dp[d];

    const int m0 = b * LSEQ + c * CT;
    for (int t = 0; t < CT; ++t) {
        const size_t m = (size_t)(m0 + t);
        const float dt = delta[m * DI + d];
        const float u  = __bfloat162float(xcb[m * DI + d]);
        const float du = dt * u;
        const float* Bp = bc + m * 32;
        const float* Cp = Bp + 16;
        float y = 0.f;
        #pragma unroll
        for (int n = 0; n < 16; ++n) {
            h[n] = h[n] * __expf(dt * a[n]) + du * Bp[n];
            y += h[n] * Cp[n];
        }
        const float z = __bfloat162float(z_bf[m * DI + d]);
        const float gt = z / (1.f + __expf(-z));
        yg[m * DI + d] = __float2bfloat16((y + u * Dv) * gt);
    }
}

// ---------------------------------------------------------------------------
extern "C" void kernel_launch(void* const* d_in, const int* in_sizes, int n_in,
                              void* d_out, int out_size, void* d_ws, size_t ws_size,
                              hipStream_t stream) {
    const float* x          = (const float*)d_in[0];
    const float* proj_in_w  = (const float*)d_in[1];
    const float* proj_in_b  = (const float*)d_in[2];
    const float* ln_gamma   = (const float*)d_in[3];
    const float* ln_beta    = (const float*)d_in[4];
    const float* in_proj_w  = (const float*)d_in[5];
    const float* conv_w     = (const float*)d_in[6];
    const float* conv_b     = (const float*)d_in[7];
    const float* x_proj_w   = (const float*)d_in[8];
    const float* dt_proj_w  = (const float*)d_in[9];
    const float* dt_proj_b  = (const float*)d_in[10];
    const float* A_log      = (const float*)d_in[11];
    const float* Dvec       = (const float*)d_in[12];
    const float* out_proj_w = (const float*)d_in[13];
    const float* res_scale  = (const float*)d_in[14];
    const float* out_gamma  = (const float*)d_in[15];
    const float* out_beta   = (const float*)d_in[16];

    float* ws     = (float*)d_ws;
    float* h_buf  = ws;                     // 2097152
    float* delta  = h_buf + 2097152;        // 4194304
    float* bc     = delta + 4194304;        // 262144
    float* Sbuf   = bc    + 262144;         // 4194304 (NC=64)
    float* Dsum   = Sbuf  + 4194304;        // 262144
    float* fend   = Dsum  + 262144;
    __hip_bfloat16* ln_bf    = (__hip_bfloat16*)fend;     // 2097152
    __hip_bfloat16* xi_bf    = ln_bf    + 2097152;        // 4194304
    __hip_bfloat16* z_bf     = xi_bf    + 4194304;        // 4194304
    __hip_bfloat16* xcb      = z_bf     + 4194304;        // 4194304
    __hip_bfloat16* yg_bf    = xcb      + 4194304;        // 4194304
    __hip_bfloat16* w_in_bf  = yg_bf    + 4194304;        // 1048576
    __hip_bfloat16* w_out_bf = w_in_bf  + 1048576;        // 524288
    __hip_bfloat16* Wc       = w_out_bf + 524288;         // 1114112
    __hip_bfloat16* x_pad    = Wc       + 1114112;        // 786432
    __hip_bfloat16* w_pi     = x_pad    + 786432;         // 24576

    // ---- one-time weight prep ----
    cvt_bf16_kernel<<<(4 * 1024 * 256 / 8 + 255) / 256, 256, 0, stream>>>(
        in_proj_w, w_in_bf, 4 * 1024 * 256);
    cvt_bf16_kernel<<<(4 * 256 * 512 / 8 + 255) / 256, 256, 0, stream>>>(
        out_proj_w, w_out_bf, 4 * 256 * 512);
    prep_wcomb<<<(4 * 544 * 512) / 256, 256, 0, stream>>>(x_proj_w, dt_proj_w, Wc);
    cvt_pad_bf16<<<(8192 * 96 + 255) / 256, 256, 0, stream>>>(x, x_pad, 8192, 80, 96);
    cvt_pad_bf16<<<(256 * 96 + 255) / 256, 256, 0, stream>>>(proj_in_w, w_pi, 256, 80, 96);

    // h = x @ proj_in_w^T + b  (bf16 MFMA, K padded to 96)
    gemm_bt16<0><<<dim3(128, 4), 256, 0, stream>>>(
        x_pad, w_pi, proj_in_b, nullptr, h_buf, nullptr, nullptr, M_ROWS, DM, 96);

    for (int i = 0; i < 4; ++i) {
        const __hip_bfloat16* in_w = w_in_bf + (size_t)i * 1024 * 256;
        const __hip_bfloat16* ow   = w_out_bf + (size_t)i * 256 * 512;
        const __hip_bfloat16* Wci  = Wc + (size_t)i * 544 * 512;
        const float* cw  = conv_w    + (size_t)i * DI * 4;
        const float* cb  = conv_b    + (size_t)i * DI;
        const float* dtb = dt_proj_b + (size_t)i * DI;
        const float* Al  = A_log     + (size_t)i * DI * DS;
        const float* Dl  = Dvec      + (size_t)i * DI;

        ln_kernel<__hip_bfloat16><<<M_ROWS, 64, 0, stream>>>(
            h_buf, ln_gamma + i * DM, ln_beta + i * DM, ln_bf);
        // xi/z = ln @ in_w^T, split bf16 outputs (M=8192 N=1024 K=256)
        gemm_bt16<2><<<dim3(128, 16), 256, 0, stream>>>(
            ln_bf, in_w, nullptr, nullptr, nullptr, xi_bf, z_bf, M_ROWS, 1024, DM);
        conv_silu3<<<(M_ROWS * DI / 8) / 256, 256, 0, stream>>>(xi_bf, cw, cb, xcb);
        gemm_dt_bc<<<dim3(128, 9), 256, 0, stream>>>(xcb, Wci, dtb, delta, bc);

        scan_part1<<<8 * NC * 2, 256, 0, stream>>>(delta, xcb, bc, Al, Sbuf, Dsum);
        scan_part2<<<(8 * DI * 16) / 256, 256, 0, stream>>>(Al, Dsum, Sbuf);
        scan_part3<<<8 * NC * 2, 256, 0, stream>>>(delta, xcb, bc, z_bf, Al, Dl,
                                                   Sbuf, yg_bf);

        // h += res_scale * (yg @ ow^T)  (M=8192 N=256 K=512)
        gemm_bt16<1><<<dim3(128, 4), 256, 0, stream>>>(
            yg_bf, ow, nullptr, res_scale, h_buf, nullptr, nullptr, M_ROWS, DM, DI);
    }

    ln_kernel<float><<<M_ROWS, 64, 0, stream>>>(h_buf, out_gamma, out_beta,
                                                (float*)d_out);
}

// Round 6
// 463.405 us; speedup vs baseline: 1.5332x; 1.5332x over previous
//
#include <hip/hip_runtime.h>
#include <hip/hip_bf16.h>

#define M_ROWS 8192      // B*L
#define DM 256           // D_MODEL
#define DI 512           // D_INNER
#define DS 16            // D_STATE
#define DTR 16           // DT_RANK
#define LSEQ 1024
#define NC 64            // chunks per sequence
#define CT 16            // chunk length (NC*CT == LSEQ)

typedef __bf16 bf16x8 __attribute__((ext_vector_type(8)));
typedef float  f32x4  __attribute__((ext_vector_type(4)));

__device__ __forceinline__ bf16x8 ld8(const __hip_bfloat16* p) {
    uint4 u = *(const uint4*)p;
    return __builtin_bit_cast(bf16x8, u);
}

// Fragment-packed layout: matrix X[R][K] stored as 1KB tiles (16 rows x 32 k).
// tile index = (r>>4)*KT + (k>>5), within tile: lane = ((k>>3)&3)*16 + (r&15),
// elem = k&7.  KT = K/32.
__device__ __forceinline__ size_t pk_off(int r, int k, int KT) {
    return ((size_t)((r >> 4) * KT + (k >> 5)) << 9)
         + (size_t)((((((k >> 3) & 3) << 4) + (r & 15)) << 3) + (k & 7));
}

// ---------------------------------------------------------------------------
// Packed bf16 MFMA GEMM. A: MxK packed. W: NxK packed. Per-wave 32(M)x64(N),
// 4 waves stacked in M -> block tile 128x64. All loads fully coalesced.
// MODE 0: C fp32 = acc + bias[n]
// MODE 1: C fp32 += alpha * acc
// MODE 2: split bf16 linear: col<DI -> O1, else O2 (N=1024)
// MODE 3: col<512 -> delta = softplus(acc+bias), col>=512 -> bcout[row*64+col-512]
// ---------------------------------------------------------------------------
template<int MODE>
__global__ __launch_bounds__(256)
void gemm_pk(const __hip_bfloat16* __restrict__ A,
             const __hip_bfloat16* __restrict__ W,
             const float* __restrict__ bias,
             const float* __restrict__ alpha_p,
             float* __restrict__ C,
             __hip_bfloat16* __restrict__ O1,
             __hip_bfloat16* __restrict__ O2,
             float* __restrict__ bcout,
             int M, int N, int K)
{
    const int KT = K >> 5;
    const int w  = threadIdx.x >> 6;
    const int l  = threadIdx.x & 63;
    const int lr = l & 15;
    const int kb = l >> 4;
    const int m0 = blockIdx.x * 128 + w * 32;
    const int n0 = blockIdx.y * 64;

    f32x4 acc[2][4];
    #pragma unroll
    for (int mi = 0; mi < 2; ++mi)
        #pragma unroll
        for (int ni = 0; ni < 4; ++ni)
            acc[mi][ni] = (f32x4){0.f, 0.f, 0.f, 0.f};

    const size_t wstep = (size_t)KT << 9;
    const __hip_bfloat16* pA0 = A + ((size_t)(m0 >> 4) * KT << 9) + l * 8;
    const __hip_bfloat16* pA1 = pA0 + wstep;
    const __hip_bfloat16* pW0 = W + ((size_t)(n0 >> 4) * KT << 9) + l * 8;

    #pragma unroll 2
    for (int kt = 0; kt < KT; ++kt) {
        const size_t o = (size_t)kt << 9;
        bf16x8 a0 = ld8(pA0 + o);
        bf16x8 a1 = ld8(pA1 + o);
        bf16x8 b0 = ld8(pW0 + o);
        bf16x8 b1 = ld8(pW0 + wstep + o);
        bf16x8 b2 = ld8(pW0 + 2 * wstep + o);
        bf16x8 b3 = ld8(pW0 + 3 * wstep + o);

        acc[0][0] = __builtin_amdgcn_mfma_f32_16x16x32_bf16(a0, b0, acc[0][0], 0, 0, 0);
        acc[1][0] = __builtin_amdgcn_mfma_f32_16x16x32_bf16(a1, b0, acc[1][0], 0, 0, 0);
        acc[0][1] = __builtin_amdgcn_mfma_f32_16x16x32_bf16(a0, b1, acc[0][1], 0, 0, 0);
        acc[1][1] = __builtin_amdgcn_mfma_f32_16x16x32_bf16(a1, b1, acc[1][1], 0, 0, 0);
        acc[0][2] = __builtin_amdgcn_mfma_f32_16x16x32_bf16(a0, b2, acc[0][2], 0, 0, 0);
        acc[1][2] = __builtin_amdgcn_mfma_f32_16x16x32_bf16(a1, b2, acc[1][2], 0, 0, 0);
        acc[0][3] = __builtin_amdgcn_mfma_f32_16x16x32_bf16(a0, b3, acc[0][3], 0, 0, 0);
        acc[1][3] = __builtin_amdgcn_mfma_f32_16x16x32_bf16(a1, b3, acc[1][3], 0, 0, 0);
    }

    const float alpha = (MODE == 1 && alpha_p) ? alpha_p[0] : 1.0f;
    #pragma unroll
    for (int mi = 0; mi < 2; ++mi) {
        #pragma unroll
        for (int ni = 0; ni < 4; ++ni) {
            const int col = n0 + ni * 16 + lr;
            const float bv = ((MODE == 0 || MODE == 3) && bias && col < 512) ? bias[col] : 0.f;
            #pragma unroll
            for (int r = 0; r < 4; ++r) {
                const int row = m0 + mi * 16 + kb * 4 + r;
                float v = acc[mi][ni][r];
                if (MODE == 0) {
                    C[(size_t)row * N + col] = v + (bias ? bias[col] : 0.f);
                } else if (MODE == 1) {
                    C[(size_t)row * N + col] += alpha * v;
                } else if (MODE == 2) {
                    if (col < DI) O1[(size_t)row * DI + col] = __float2bfloat16(v);
                    else          O2[(size_t)row * DI + (col - DI)] = __float2bfloat16(v);
                } else {
                    if (col < 512) {
                        v += bv;
                        v = (v > 15.f) ? v : __logf(1.f + __expf(v));
                        C[(size_t)row * DI + col] = v;
                    } else {
                        bcout[(size_t)row * 64 + (col - 512)] = v;
                    }
                }
            }
        }
    }
}

// ---------------------------------------------------------------------------
// Pack fp32 matrix (Nsrc x Ksrc) into fragment-packed bf16 (Npad x Kpad),
// zero-filling pad. One thread per packed element; coalesced writes.
// ---------------------------------------------------------------------------
__global__ __launch_bounds__(256)
void pack_w(const float* __restrict__ src, __hip_bfloat16* __restrict__ dst,
            int Nsrc, int Ksrc, int Npad, int Kpad)
{
    const int idx = blockIdx.x * 256 + threadIdx.x;
    if (idx >= Npad * Kpad) return;
    const int KT = Kpad >> 5;
    const int t = idx >> 9;
    const int lane = (idx >> 3) & 63;
    const int e = idx & 7;
    const int rt = t / KT;
    const int kt = t - rt * KT;
    const int r_ = rt * 16 + (lane & 15);
    const int k_ = kt * 32 + (lane >> 4) * 8 + e;
    const float v = (r_ < Nsrc && k_ < Ksrc) ? src[(size_t)r_ * Ksrc + k_] : 0.f;
    dst[idx] = __float2bfloat16(v);
}

// ---------------------------------------------------------------------------
// Build packed W_comb (per layer 576x512): rows 0..511 = dtw @ xw[0:16];
// rows 512..543 = xw[16:48]; rows 544..575 = 0.
// ---------------------------------------------------------------------------
__global__ __launch_bounds__(256)
void prep_wcomb_pk(const float* __restrict__ xw, const float* __restrict__ dtw,
                   __hip_bfloat16* __restrict__ Wc)
{
    const int idx = blockIdx.x * 256 + threadIdx.x;   // 4*576*512
    const int lyr = idx / (576 * 512);
    const int rem = idx - lyr * (576 * 512);
    const int KT = 16;
    const int t = rem >> 9;
    const int lane = (rem >> 3) & 63;
    const int e = rem & 7;
    const int rt = t / KT;
    const int kt = t - rt * KT;
    const int n = rt * 16 + (lane & 15);
    const int k = kt * 32 + (lane >> 4) * 8 + e;

    const float* xwl = xw + (size_t)lyr * 48 * 512;
    float s = 0.f;
    if (n < 512) {
        const float* dtn = dtw + (size_t)lyr * 512 * 16 + n * 16;
        #pragma unroll
        for (int r = 0; r < 16; ++r) s += dtn[r] * xwl[r * 512 + k];
    } else if (n < 544) {
        s = xwl[(16 + n - 512) * 512 + k];
    }
    Wc[idx] = __float2bfloat16(s);
}

// ---------------------------------------------------------------------------
// LayerNorm rows of 256; OM 0: fp32 linear out, OM 1: packed bf16 out (KT=8).
// ---------------------------------------------------------------------------
template<int OM>
__global__ __launch_bounds__(64)
void ln_kernel(const float* __restrict__ in, const float* __restrict__ g,
               const float* __restrict__ b, void* __restrict__ outv)
{
    const int row = blockIdx.x;
    const int t = threadIdx.x;
    const float* x = in + (size_t)row * DM;

    float v[4];
    float s = 0.f;
    #pragma unroll
    for (int j = 0; j < 4; ++j) { v[j] = x[t + 64 * j]; s += v[j]; }
    #pragma unroll
    for (int m = 1; m < 64; m <<= 1) s += __shfl_xor(s, m, 64);
    const float mu = s * (1.f / DM);

    float s2 = 0.f;
    #pragma unroll
    for (int j = 0; j < 4; ++j) { float d = v[j] - mu; s2 += d * d; }
    #pragma unroll
    for (int m = 1; m < 64; m <<= 1) s2 += __shfl_xor(s2, m, 64);
    const float var = s2 * (1.f / DM);
    const float sc = 1.f / sqrtf(var + 1e-5f);

    #pragma unroll
    for (int j = 0; j < 4; ++j) {
        const int c = t + 64 * j;
        const float o = (v[j] - mu) * sc * g[c] + b[c];
        if (OM == 0) ((float*)outv)[(size_t)row * DM + c] = o;
        else ((__hip_bfloat16*)outv)[pk_off(row, c, 8)] = __float2bfloat16(o);
    }
}

// ---------------------------------------------------------------------------
// Rolling causal conv4 + SiLU: xi linear bf16 in, xcb packed bf16 out (KT=16).
// ---------------------------------------------------------------------------
__global__ __launch_bounds__(256)
void conv_silu3(const __hip_bfloat16* __restrict__ xi, const float* __restrict__ cw,
                const float* __restrict__ cb, __hip_bfloat16* __restrict__ xcb)
{
    const int idx = blockIdx.x * 256 + threadIdx.x;   // 8192*512/8
    const int d = idx & (DI - 1);
    const int g = idx >> 9;
    const int b = g >> 7;
    const int l0 = (g & 127) * 8;

    const float w0 = cw[d * 4 + 0], w1 = cw[d * 4 + 1];
    const float w2 = cw[d * 4 + 2], w3 = cw[d * 4 + 3];
    const float bias = cb[d];

    const size_t base = ((size_t)b << 10);
    float xm3 = (l0 >= 3) ? __bfloat162float(xi[(base + l0 - 3) * DI + d]) : 0.f;
    float xm2 = (l0 >= 2) ? __bfloat162float(xi[(base + l0 - 2) * DI + d]) : 0.f;
    float xm1 = (l0 >= 1) ? __bfloat162float(xi[(base + l0 - 1) * DI + d]) : 0.f;

    #pragma unroll
    for (int j = 0; j < 8; ++j) {
        const size_t m = base + l0 + j;
        const float xc0 = __bfloat162float(xi[m * DI + d]);
        float acc = bias + w0 * xm3 + w1 * xm2 + w2 * xm1 + w3 * xc0;
        const float sg = 1.f / (1.f + __expf(-acc));
        xcb[pk_off((int)m, d, 16)] = __float2bfloat16(acc * sg);
        xm3 = xm2; xm2 = xm1; xm1 = xc0;
    }
}

// ---------------------------------------------------------------------------
// Chunked parallel selective scan. u from packed xcb; bc is 64-wide [B16|C16|slop].
// ---------------------------------------------------------------------------
__global__ __launch_bounds__(256)
void scan_part1(const float* __restrict__ delta, const __hip_bfloat16* __restrict__ xcb,
                const float* __restrict__ bc, const float* __restrict__ A_log,
                float* __restrict__ S, float* __restrict__ Dsum)
{
    const int blk = blockIdx.x;
    const int bcx = blk >> 1;
    const int d   = ((blk & 1) << 8) + threadIdx.x;
    const int b   = bcx >> 6;
    const int c   = bcx & (NC - 1);

    float a[16], h[16];
    #pragma unroll
    for (int n = 0; n < 16; ++n) {
        a[n] = -__expf(A_log[d * 16 + n]);
        h[n] = 0.f;
    }
    float dsum = 0.f;

    const int m0 = b * LSEQ + c * CT;
    for (int t = 0; t < CT; ++t) {
        const int m = m0 + t;
        const float dt = delta[(size_t)m * DI + d];
        const float u  = __bfloat162float(xcb[pk_off(m, d, 16)]);
        const float du = dt * u;
        dsum += dt;
        const float* Bp = bc + (size_t)m * 64;
        #pragma unroll
        for (int n = 0; n < 16; ++n)
            h[n] = h[n] * __expf(dt * a[n]) + du * Bp[n];
    }
    float* Sp = S + ((size_t)bcx * DI + d) * 16;
    #pragma unroll
    for (int n = 0; n < 16; ++n) Sp[n] = h[n];
    Dsum[(size_t)bcx * DI + d] = dsum;
}

__global__ __launch_bounds__(256)
void scan_part2(const float* __restrict__ A_log, const float* __restrict__ Dsum,
                float* __restrict__ S)
{
    const int gid = blockIdx.x * 256 + threadIdx.x;
    const int n = gid & 15;
    const int d = (gid >> 4) & (DI - 1);
    const int b = gid >> 13;

    const float a = -__expf(A_log[d * 16 + n]);
    float h = 0.f;
    for (int c = 0; c < NC; ++c) {
        const size_t bcd = (size_t)(b * NC + c) * DI + d;
        const size_t idx = bcd * 16 + n;
        const float s = S[idx];
        S[idx] = h;
        h = __expf(a * Dsum[bcd]) * h + s;
    }
}

__global__ __launch_bounds__(256)
void scan_part3(const float* __restrict__ delta, const __hip_bfloat16* __restrict__ xcb,
                const float* __restrict__ bc, const __hip_bfloat16* __restrict__ z_bf,
                const float* __restrict__ A_log, const float* __restrict__ Dp,
                const float* __restrict__ H, __hip_bfloat16* __restrict__ yg)
{
    const int blk = blockIdx.x;
    const int bcx = blk >> 1;
    const int d   = ((blk & 1) << 8) + threadIdx.x;
    const int b   = bcx >> 6;
    const int c   = bcx & (NC - 1);

    float a[16], h[16];
    const float* Hp = H + ((size_t)bcx * DI + d) * 16;
    #pragma unroll
    for (int n = 0; n < 16; ++n) {
        a[n] = -__expf(A_log[d * 16 + n]);
        h[n] = Hp[n];
    }
    const float Dv = Dp[d];

    const int m0 = b * LSEQ + c * CT;
    for (int t = 0; t < CT; ++t) {
        const int m = m0 + t;
        const float dt = delta[(size_t)m * DI + d];
        const float u  = __bfloat162float(xcb[pk_off(m, d, 16)]);
        const float du = dt * u;
        const float* Bp = bc + (size_t)m * 64;
        const float* Cp = Bp + 16;
        float y = 0.f;
        #pragma unroll
        for (int n = 0; n < 16; ++n) {
            h[n] = h[n] * __expf(dt * a[n]) + du * Bp[n];
            y += h[n] * Cp[n];
        }
        const float z = __bfloat162float(z_bf[(size_t)m * DI + d]);
        const float gt = z / (1.f + __expf(-z));
        yg[pk_off(m, d, 16)] = __float2bfloat16((y + u * Dv) * gt);
    }
}

// ---------------------------------------------------------------------------
extern "C" void kernel_launch(void* const* d_in, const int* in_sizes, int n_in,
                              void* d_out, int out_size, void* d_ws, size_t ws_size,
                              hipStream_t stream) {
    const float* x          = (const float*)d_in[0];
    const float* proj_in_w  = (const float*)d_in[1];
    const float* proj_in_b  = (const float*)d_in[2];
    const float* ln_gamma   = (const float*)d_in[3];
    const float* ln_beta    = (const float*)d_in[4];
    const float* in_proj_w  = (const float*)d_in[5];
    const float* conv_w     = (const float*)d_in[6];
    const float* conv_b     = (const float*)d_in[7];
    const float* x_proj_w   = (const float*)d_in[8];
    const float* dt_proj_w  = (const float*)d_in[9];
    const float* dt_proj_b  = (const float*)d_in[10];
    const float* A_log      = (const float*)d_in[11];
    const float* Dvec       = (const float*)d_in[12];
    const float* out_proj_w = (const float*)d_in[13];
    const float* res_scale  = (const float*)d_in[14];
    const float* out_gamma  = (const float*)d_in[15];
    const float* out_beta   = (const float*)d_in[16];

    float* ws     = (float*)d_ws;
    float* h_buf  = ws;                     // 2097152
    float* delta  = h_buf + 2097152;        // 4194304
    float* bc     = delta + 4194304;        // 524288 (8192*64)
    float* Sbuf   = bc    + 524288;         // 4194304
    float* Dsum   = Sbuf  + 4194304;        // 262144
    float* fend   = Dsum  + 262144;
    __hip_bfloat16* ln_pk    = (__hip_bfloat16*)fend;     // 2097152
    __hip_bfloat16* xi_bf    = ln_pk    + 2097152;        // 4194304 (linear)
    __hip_bfloat16* z_bf     = xi_bf    + 4194304;        // 4194304 (linear)
    __hip_bfloat16* xcb_pk   = z_bf     + 4194304;        // 4194304
    __hip_bfloat16* yg_pk    = xcb_pk   + 4194304;        // 4194304
    __hip_bfloat16* w_in_pk  = yg_pk    + 4194304;        // 1048576
    __hip_bfloat16* w_out_pk = w_in_pk  + 1048576;        // 524288
    __hip_bfloat16* Wc_pk    = w_out_pk + 524288;         // 1179648 (4*576*512)
    __hip_bfloat16* x_pk     = Wc_pk    + 1179648;        // 786432  (8192*96)
    __hip_bfloat16* w_pi_pk  = x_pk     + 786432;         // 24576   (256*96)

    // ---- one-time packing ----
    pack_w<<<(4096 * 256) / 256, 256, 0, stream>>>(in_proj_w, w_in_pk, 4096, 256, 4096, 256);
    pack_w<<<(1024 * 512) / 256, 256, 0, stream>>>(out_proj_w, w_out_pk, 1024, 512, 1024, 512);
    prep_wcomb_pk<<<(4 * 576 * 512) / 256, 256, 0, stream>>>(x_proj_w, dt_proj_w, Wc_pk);
    pack_w<<<(8192 * 96) / 256, 256, 0, stream>>>(x, x_pk, 8192, 80, 8192, 96);
    pack_w<<<(256 * 96) / 256, 256, 0, stream>>>(proj_in_w, w_pi_pk, 256, 80, 256, 96);

    // h = x @ proj_in_w^T + b  (M=8192 N=256 K=96)
    gemm_pk<0><<<dim3(64, 4), 256, 0, stream>>>(
        x_pk, w_pi_pk, proj_in_b, nullptr, h_buf, nullptr, nullptr, nullptr,
        M_ROWS, DM, 96);

    for (int i = 0; i < 4; ++i) {
        const __hip_bfloat16* in_w = w_in_pk + (size_t)i * 1024 * 256;
        const __hip_bfloat16* ow   = w_out_pk + (size_t)i * 256 * 512;
        const __hip_bfloat16* Wci  = Wc_pk + (size_t)i * 576 * 512;
        const float* cw  = conv_w    + (size_t)i * DI * 4;
        const float* cb  = conv_b    + (size_t)i * DI;
        const float* dtb = dt_proj_b + (size_t)i * DI;
        const float* Al  = A_log     + (size_t)i * DI * DS;
        const float* Dl  = Dvec      + (size_t)i * DI;

        ln_kernel<1><<<M_ROWS, 64, 0, stream>>>(h_buf, ln_gamma + i * DM,
                                                ln_beta + i * DM, ln_pk);
        // xi/z = ln @ in_w^T  (M=8192 N=1024 K=256), split linear bf16 out
        gemm_pk<2><<<dim3(64, 16), 256, 0, stream>>>(
            ln_pk, in_w, nullptr, nullptr, nullptr, xi_bf, z_bf, nullptr,
            M_ROWS, 1024, DM);
        conv_silu3<<<(M_ROWS * DI / 8) / 256, 256, 0, stream>>>(xi_bf, cw, cb, xcb_pk);
        // delta/bc = xc @ Wc^T  (M=8192 N=576 K=512)
        gemm_pk<3><<<dim3(64, 9), 256, 0, stream>>>(
            xcb_pk, Wci, dtb, nullptr, delta, nullptr, nullptr, bc,
            M_ROWS, 576, DI);

        scan_part1<<<8 * NC * 2, 256, 0, stream>>>(delta, xcb_pk, bc, Al, Sbuf, Dsum);
        scan_part2<<<(8 * DI * 16) / 256, 256, 0, stream>>>(Al, Dsum, Sbuf);
        scan_part3<<<8 * NC * 2, 256, 0, stream>>>(delta, xcb_pk, bc, z_bf, Al, Dl,
                                                   Sbuf, yg_pk);

        // h += res_scale * (yg @ ow^T)  (M=8192 N=256 K=512)
        gemm_pk<1><<<dim3(64, 4), 256, 0, stream>>>(
            yg_pk, ow, nullptr, res_scale, h_buf, nullptr, nullptr, nullptr,
            M_ROWS, DM, DI);
    }

    ln_kernel<0><<<M_ROWS, 64, 0, stream>>>(h_buf, out_gamma, out_beta, d_out);
}